// Round 3
// baseline (913.532 us; speedup 1.0000x reference)
//
#include <hip/hip_runtime.h>
#include <hip/hip_bf16.h>
#include <math.h>

#define NROWS 16384
#define HID 64

typedef __attribute__((ext_vector_type(8))) __bf16 bf16x8;
typedef __attribute__((ext_vector_type(4))) float f32x4;

__device__ inline f32x4 mfma16(bf16x8 a, bf16x8 b, f32x4 c) {
    return __builtin_amdgcn_mfma_f32_16x16x32_bf16(a, b, c, 0, 0, 0);
}

__device__ inline void split8v(const f32x4 v0, const f32x4 v1, bf16x8& h, bf16x8& l) {
    float f[8] = {v0[0], v0[1], v0[2], v0[3], v1[0], v1[1], v1[2], v1[3]};
#pragma unroll
    for (int j = 0; j < 8; ++j) {
        __bf16 hh = (__bf16)f[j];
        h[j] = hh;
        l[j] = (__bf16)(f[j] - (float)hh);
    }
}

// ---------------------------------------------------------------------------
// pack_b: x [16384,64] fp32 row-major  ->  MFMA B-fragment-ordered bf16 hi/lo.
// Packed index: (((kb*4 + t)*64 + lane)*8 + j)
//   holds x[kb*32 + (lane>>4)*8 + j][t*16 + (lane&15)]
// so the consumer does one contiguous 16B load per lane (coalesced 1KB/wave).
// ---------------------------------------------------------------------------
__global__ __launch_bounds__(256) void pack_b(const float* __restrict__ x,
                                              __bf16* __restrict__ hi,
                                              __bf16* __restrict__ lo) {
    __shared__ float tile[32 * 64];
    const int kb = blockIdx.x;  // 0..511, 32 k-rows each
    const f32x4* src = (const f32x4*)(x + (size_t)kb * 32 * 64);
    f32x4* dst = (f32x4*)tile;
    dst[threadIdx.x] = src[threadIdx.x];
    dst[threadIdx.x + 256] = src[threadIdx.x + 256];
    __syncthreads();
    const int t = threadIdx.x >> 6;    // n-tile 0..3
    const int l = threadIdx.x & 63;    // consumer lane
    const int col = (t << 4) + (l & 15);
    const int krow = (l >> 4) * 8;
    bf16x8 h8, l8;
#pragma unroll
    for (int j = 0; j < 8; ++j) {
        float v = tile[(krow + j) * 64 + col];
        __bf16 hh = (__bf16)v;
        h8[j] = hh;
        l8[j] = (__bf16)(v - (float)hh);
    }
    const size_t base = (((size_t)kb * 4 + t) * 64 + l) * 8;
    *(bf16x8*)(hi + base) = h8;
    *(bf16x8*)(lo + base) = l8;
}

// ---------------------------------------------------------------------------
// gemm_agg: agg = adj @ x  via bf16 hi/lo split MFMA (3 MFMAs per tile-pair).
// 1024 blocks x 16 rows; 4 waves per block each own K/4 (4096 k-elems).
// 4 blocks/CU -> 4 waves/SIMD for HBM latency hiding.
// A fragments loaded straight from global fp32 (16 rows x 128B contiguous per
// k-step, non-temporal so the adj stream doesn't evict packed-B from L2) and
// split to bf16 hi/lo in registers. Cross-wave K-reduction through LDS.
// ---------------------------------------------------------------------------
__global__ __launch_bounds__(256, 4) void gemm_agg(const float* __restrict__ adj,
                                                   const __bf16* __restrict__ Bhi,
                                                   const __bf16* __restrict__ Blo,
                                                   float* __restrict__ agg) {
    __shared__ float red[4][16][64];  // 16 KB

    const int lane = threadIdx.x & 63;
    const int wv = threadIdx.x >> 6;  // 0..3 : K-chunk owner
    const int rbase = blockIdx.x * 16;
    const int rq = lane & 15;   // row within 16-row group
    const int kq = lane >> 4;   // k-quarter 0..3

    f32x4 acc[4];
#pragma unroll
    for (int t = 0; t < 4; ++t) acc[t] = f32x4{0.f, 0.f, 0.f, 0.f};

    const float* ap = adj + (size_t)(rbase + rq) * NROWS + kq * 8;
    const int k0 = wv * (NROWS / 4);

    for (int kk = k0; kk < k0 + NROWS / 4; kk += 32) {
        // B fragments (L2-resident packed bf16), 8 x 16B coalesced loads
        const size_t bb = ((size_t)(kk >> 5) * 4) * 512 + (size_t)lane * 8;
        bf16x8 bh[4], bl[4];
#pragma unroll
        for (int t = 0; t < 4; ++t) {
            bh[t] = *(const bf16x8*)(Bhi + bb + (size_t)t * 512);
            bl[t] = *(const bf16x8*)(Blo + bb + (size_t)t * 512);
        }
        // A: 8 fp32 per lane, contiguous 32B, non-temporal (streaming)
        const f32x4* app = (const f32x4*)(ap + kk);
        f32x4 v0 = __builtin_nontemporal_load(app);
        f32x4 v1 = __builtin_nontemporal_load(app + 1);
        bf16x8 ah, al;
        split8v(v0, v1, ah, al);

#pragma unroll
        for (int t = 0; t < 4; ++t) {
            acc[t] = mfma16(ah, bh[t], acc[t]);
            acc[t] = mfma16(ah, bl[t], acc[t]);
            acc[t] = mfma16(al, bh[t], acc[t]);
        }
    }

    // C/D layout: col = lane&15, row = (lane>>4)*4 + reg   [m89-verified]
#pragma unroll
    for (int t = 0; t < 4; ++t)
#pragma unroll
        for (int r = 0; r < 4; ++r)
            red[wv][kq * 4 + r][t * 16 + (lane & 15)] = acc[t][r];
    __syncthreads();

    // 1024 floats / 256 threads = 4 each (one f32x4); sum 4 K-chunks
    const int row = threadIdx.x >> 4;
    const int c0 = (threadIdx.x & 15) * 4;
    f32x4 s = f32x4{0.f, 0.f, 0.f, 0.f};
#pragma unroll
    for (int w = 0; w < 4; ++w) s += *(const f32x4*)&red[w][row][c0];
    *(f32x4*)(agg + (size_t)(rbase + row) * 64 + c0) = s;
}

// ---------------------------------------------------------------------------
// dense_tanh: x_out[r,h] = tanh( [agg_r | x_r] @ W ),  W is [128,64] in LDS.
// lane = output column h; concat-row values broadcast via __shfl.
// ---------------------------------------------------------------------------
__global__ __launch_bounds__(256) void dense_tanh(const float* __restrict__ agg,
                                                  const float* __restrict__ xin,
                                                  const float* __restrict__ W,
                                                  float* __restrict__ xout) {
    __shared__ float wsm[128 * 64];  // 32 KB
    const f32x4* wsrc = (const f32x4*)W;
    f32x4* wdst = (f32x4*)wsm;
#pragma unroll
    for (int i = 0; i < 8; ++i) wdst[threadIdx.x + 256 * i] = wsrc[threadIdx.x + 256 * i];
    __syncthreads();

    const int lane = threadIdx.x & 63;
    const int wv = threadIdx.x >> 6;
    const int r0 = blockIdx.x * 32 + wv * 8;
#pragma unroll 2
    for (int i = 0; i < 8; ++i) {
        const int r = r0 + i;
        const float av = agg[(size_t)r * 64 + lane];
        const float xv = xin[(size_t)r * 64 + lane];
        float z = 0.f;
#pragma unroll
        for (int j = 0; j < 64; ++j) z += __shfl(av, j) * wsm[j * 64 + lane];
#pragma unroll
        for (int j = 0; j < 64; ++j) z += __shfl(xv, j) * wsm[(64 + j) * 64 + lane];
        xout[(size_t)r * 64 + lane] = tanhf(z);
    }
}

extern "C" void kernel_launch(void* const* d_in, const int* in_sizes, int n_in,
                              void* d_out, int out_size, void* d_ws, size_t ws_size,
                              hipStream_t stream) {
    const float* x0 = (const float*)d_in[0];   // user_embs [16384,64]
    const float* adj = (const float*)d_in[1];  // adj [16384,16384]
    const float* W = (const float*)d_in[2];    // W [2,128,64]
    float* out = (float*)d_out;

    char* ws = (char*)d_ws;
    __bf16* Bhi = (__bf16*)(ws);                      // 2 MB
    __bf16* Blo = (__bf16*)(ws + (2u << 20));         // 2 MB
    float* agg = (float*)(ws + (4u << 20));           // 4 MB
    float* x1 = (float*)(ws + (8u << 20));            // 4 MB

    // hop 0
    pack_b<<<512, 256, 0, stream>>>(x0, Bhi, Blo);
    gemm_agg<<<1024, 256, 0, stream>>>(adj, Bhi, Blo, agg);
    dense_tanh<<<512, 256, 0, stream>>>(agg, x0, W, x1);
    // hop 1
    pack_b<<<512, 256, 0, stream>>>(x1, Bhi, Blo);
    gemm_agg<<<1024, 256, 0, stream>>>(adj, Bhi, Blo, agg);
    dense_tanh<<<512, 256, 0, stream>>>(agg, x1, W + 128 * 64, out);
}

// Round 4
// 887.381 us; speedup vs baseline: 1.0295x; 1.0295x over previous
//
#include <hip/hip_runtime.h>
#include <hip/hip_bf16.h>
#include <math.h>

#define NROWS 16384
#define HID 64
#define KSPLIT 8
#define KCH (NROWS / KSPLIT)  // 2048

typedef __attribute__((ext_vector_type(8))) __bf16 bf16x8;
typedef __attribute__((ext_vector_type(4))) float f32x4;

__device__ inline f32x4 mfma16(bf16x8 a, bf16x8 b, f32x4 c) {
    return __builtin_amdgcn_mfma_f32_16x16x32_bf16(a, b, c, 0, 0, 0);
}

__device__ inline void split8v(const f32x4 v0, const f32x4 v1, bf16x8& h, bf16x8& l) {
    float f[8] = {v0[0], v0[1], v0[2], v0[3], v1[0], v1[1], v1[2], v1[3]};
#pragma unroll
    for (int j = 0; j < 8; ++j) {
        __bf16 hh = (__bf16)f[j];
        h[j] = hh;
        l[j] = (__bf16)(f[j] - (float)hh);
    }
}

// ---------------------------------------------------------------------------
// pack_b: x [16384,64] fp32 row-major  ->  MFMA B-fragment-ordered bf16 hi/lo.
// Packed index: (((kb*4 + t)*64 + lane)*8 + j)
//   holds x[kb*32 + (lane>>4)*8 + j][t*16 + (lane&15)]
// ---------------------------------------------------------------------------
__global__ __launch_bounds__(256) void pack_b(const float* __restrict__ x,
                                              __bf16* __restrict__ hi,
                                              __bf16* __restrict__ lo) {
    __shared__ float tile[32 * 64];
    const int kb = blockIdx.x;  // 0..511, 32 k-rows each
    const f32x4* src = (const f32x4*)(x + (size_t)kb * 32 * 64);
    f32x4* dst = (f32x4*)tile;
    dst[threadIdx.x] = src[threadIdx.x];
    dst[threadIdx.x + 256] = src[threadIdx.x + 256];
    __syncthreads();
    const int t = threadIdx.x >> 6;    // n-tile 0..3
    const int l = threadIdx.x & 63;    // consumer lane
    const int col = (t << 4) + (l & 15);
    const int krow = (l >> 4) * 8;
    bf16x8 h8, l8;
#pragma unroll
    for (int j = 0; j < 8; ++j) {
        float v = tile[(krow + j) * 64 + col];
        __bf16 hh = (__bf16)v;
        h8[j] = hh;
        l8[j] = (__bf16)(v - (float)hh);
    }
    const size_t base = (((size_t)kb * 4 + t) * 64 + l) * 8;
    *(bf16x8*)(hi + base) = h8;
    *(bf16x8*)(lo + base) = l8;
}

// ---------------------------------------------------------------------------
// gemm_partial: partial[ks] = adj[:, ks-chunk] @ x[ks-chunk, :]
// Split-K across blocks: blockIdx = ks*256 + rt.  Block = 64 rows x 2048 k,
// 4 waves x 16 rows; all waves sweep the SAME k-range so B fragments are
// shared via L1/L2 (logical B traffic = 256 tiles x 4MB = 1 GB, L2-served).
// adj loads non-temporal (keep L2 for B); partial stores non-temporal
// (don't evict B with 32 MB of partials). No LDS, ~80 VGPR -> high occupancy.
// ---------------------------------------------------------------------------
__global__ __launch_bounds__(256, 4) void gemm_partial(const float* __restrict__ adj,
                                                       const __bf16* __restrict__ Bhi,
                                                       const __bf16* __restrict__ Blo,
                                                       float* __restrict__ partial) {
    const int lane = threadIdx.x & 63;
    const int wv = threadIdx.x >> 6;   // wave -> 16-row group
    const int rt = blockIdx.x & 255;   // row-tile 0..255
    const int ks = blockIdx.x >> 8;    // k-split 0..7
    const int rbase = rt * 64 + wv * 16;
    const int rq = lane & 15;          // A row within group
    const int kq = lane >> 4;          // k-quarter 0..3

    f32x4 acc[4];
#pragma unroll
    for (int t = 0; t < 4; ++t) acc[t] = f32x4{0.f, 0.f, 0.f, 0.f};

    const float* ap = adj + (size_t)(rbase + rq) * NROWS + ks * KCH + kq * 8;
    const int kk0 = ks * KCH;

    for (int kk = 0; kk < KCH; kk += 32) {
        // B fragments (L2-resident packed bf16), 8 x 16B coalesced loads
        const size_t bb = ((size_t)((kk0 + kk) >> 5) * 4) * 512 + (size_t)lane * 8;
        bf16x8 bh[4], bl[4];
#pragma unroll
        for (int t = 0; t < 4; ++t) {
            bh[t] = *(const bf16x8*)(Bhi + bb + (size_t)t * 512);
            bl[t] = *(const bf16x8*)(Blo + bb + (size_t)t * 512);
        }
        // A: 8 fp32 per lane, contiguous 32B, non-temporal (streaming)
        const f32x4* app = (const f32x4*)(ap + kk);
        f32x4 v0 = __builtin_nontemporal_load(app);
        f32x4 v1 = __builtin_nontemporal_load(app + 1);
        bf16x8 ah, al;
        split8v(v0, v1, ah, al);

#pragma unroll
        for (int t = 0; t < 4; ++t) {
            acc[t] = mfma16(ah, bh[t], acc[t]);
            acc[t] = mfma16(ah, bl[t], acc[t]);
            acc[t] = mfma16(al, bh[t], acc[t]);
        }
    }

    // C/D layout: col = lane&15, row = (lane>>4)*4 + reg   [m89-verified]
    float* pp = partial + (size_t)ks * (NROWS * HID) + (size_t)rbase * HID;
#pragma unroll
    for (int t = 0; t < 4; ++t)
#pragma unroll
        for (int r = 0; r < 4; ++r)
            __builtin_nontemporal_store(acc[t][r],
                pp + (kq * 4 + r) * HID + t * 16 + (lane & 15));
}

// ---------------------------------------------------------------------------
// reduce_dense: agg_r = sum_ks partial[ks][r]; x_out[r] = tanh([agg_r|x_r] @ W)
// W [128,64] staged in LDS; lane = output column; row values via __shfl.
// ---------------------------------------------------------------------------
__global__ __launch_bounds__(256) void reduce_dense(const float* __restrict__ partial,
                                                    const float* __restrict__ xin,
                                                    const float* __restrict__ W,
                                                    float* __restrict__ xout) {
    __shared__ float wsm[128 * 64];  // 32 KB
    const f32x4* wsrc = (const f32x4*)W;
    f32x4* wdst = (f32x4*)wsm;
#pragma unroll
    for (int i = 0; i < 8; ++i) wdst[threadIdx.x + 256 * i] = wsrc[threadIdx.x + 256 * i];
    __syncthreads();

    const int lane = threadIdx.x & 63;
    const int wv = threadIdx.x >> 6;
    const int r0 = blockIdx.x * 32 + wv * 8;
#pragma unroll 2
    for (int i = 0; i < 8; ++i) {
        const int r = r0 + i;
        float av = 0.f;
#pragma unroll
        for (int ks = 0; ks < KSPLIT; ++ks)
            av += partial[(size_t)ks * (NROWS * HID) + (size_t)r * HID + lane];
        const float xv = xin[(size_t)r * HID + lane];
        float z = 0.f;
#pragma unroll
        for (int j = 0; j < 64; ++j) z += __shfl(av, j) * wsm[j * 64 + lane];
#pragma unroll
        for (int j = 0; j < 64; ++j) z += __shfl(xv, j) * wsm[(64 + j) * 64 + lane];
        xout[(size_t)r * HID + lane] = tanhf(z);
    }
}

extern "C" void kernel_launch(void* const* d_in, const int* in_sizes, int n_in,
                              void* d_out, int out_size, void* d_ws, size_t ws_size,
                              hipStream_t stream) {
    const float* x0 = (const float*)d_in[0];   // user_embs [16384,64]
    const float* adj = (const float*)d_in[1];  // adj [16384,16384]
    const float* W = (const float*)d_in[2];    // W [2,128,64]
    float* out = (float*)d_out;

    char* ws = (char*)d_ws;
    __bf16* Bhi = (__bf16*)(ws);                       // 2 MB
    __bf16* Blo = (__bf16*)(ws + (2u << 20));          // 2 MB
    float* partial = (float*)(ws + (4u << 20));        // 32 MB (8 x 4 MB)
    float* x1 = (float*)(ws + (36u << 20));            // 4 MB

    // hop 0
    pack_b<<<512, 256, 0, stream>>>(x0, Bhi, Blo);
    gemm_partial<<<KSPLIT * 256, 256, 0, stream>>>(adj, Bhi, Blo, partial);
    reduce_dense<<<512, 256, 0, stream>>>(partial, x0, W, x1);
    // hop 1
    pack_b<<<512, 256, 0, stream>>>(x1, Bhi, Blo);
    gemm_partial<<<KSPLIT * 256, 256, 0, stream>>>(adj, Bhi, Blo, partial);
    reduce_dense<<<512, 256, 0, stream>>>(partial, x1, W + 128 * 64, out);
}

// Round 5
// 807.436 us; speedup vs baseline: 1.1314x; 1.0990x over previous
//
#include <hip/hip_runtime.h>
#include <hip/hip_bf16.h>
#include <math.h>

#define NROWS 16384
#define HID 64
#define KSPLIT 8
#define KCH (NROWS / KSPLIT)  // 2048

typedef __attribute__((ext_vector_type(8))) __bf16 bf16x8;
typedef __attribute__((ext_vector_type(4))) float f32x4;

__device__ inline f32x4 mfma16(bf16x8 a, bf16x8 b, f32x4 c) {
    return __builtin_amdgcn_mfma_f32_16x16x32_bf16(a, b, c, 0, 0, 0);
}

__device__ inline void split8v(const f32x4 v0, const f32x4 v1, bf16x8& h, bf16x8& l) {
    float f[8] = {v0[0], v0[1], v0[2], v0[3], v1[0], v1[1], v1[2], v1[3]};
#pragma unroll
    for (int j = 0; j < 8; ++j) {
        __bf16 hh = (__bf16)f[j];
        h[j] = hh;
        l[j] = (__bf16)(f[j] - (float)hh);
    }
}

// ---------------------------------------------------------------------------
// pack_b: x [16384,64] fp32 row-major  ->  MFMA B-fragment-ordered bf16 hi/lo.
// Packed index: (((kb*4 + t)*64 + lane)*8 + j)
//   holds x[kb*32 + (lane>>4)*8 + j][t*16 + (lane&15)]
// ---------------------------------------------------------------------------
__global__ __launch_bounds__(256) void pack_b(const float* __restrict__ x,
                                              __bf16* __restrict__ hi,
                                              __bf16* __restrict__ lo) {
    __shared__ float tile[32 * 64];
    const int kb = blockIdx.x;  // 0..511, 32 k-rows each
    const f32x4* src = (const f32x4*)(x + (size_t)kb * 32 * 64);
    f32x4* dst = (f32x4*)tile;
    dst[threadIdx.x] = src[threadIdx.x];
    dst[threadIdx.x + 256] = src[threadIdx.x + 256];
    __syncthreads();
    const int t = threadIdx.x >> 6;    // n-tile 0..3
    const int l = threadIdx.x & 63;    // consumer lane
    const int col = (t << 4) + (l & 15);
    const int krow = (l >> 4) * 8;
    bf16x8 h8, l8;
#pragma unroll
    for (int j = 0; j < 8; ++j) {
        float v = tile[(krow + j) * 64 + col];
        __bf16 hh = (__bf16)v;
        h8[j] = hh;
        l8[j] = (__bf16)(v - (float)hh);
    }
    const size_t base = (((size_t)kb * 4 + t) * 64 + l) * 8;
    *(bf16x8*)(hi + base) = h8;
    *(bf16x8*)(lo + base) = l8;
}

// ---------------------------------------------------------------------------
// gemm_partial: partial[ks] = adj[:, ks-chunk] @ x[ks-chunk, :]
// Split-K across blocks: blockIdx = ks*256 + rt.  Block = 64 rows x 2048 k,
// 4 waves x 16 rows; all waves sweep the SAME k-range so B fragments are
// L1/L2-shared. adj loads are PLAIN (L1-allocating): each lane's v0/v1 pair
// covers half a 128B line each, so the L1 line allocated by v0 must serve v1
// -- nontemporal here double-fetched every adj line from HBM (rounds 3/4
// regression). Partial stores stay nt (no reuse; keep L2 for B).
// ---------------------------------------------------------------------------
__global__ __launch_bounds__(256, 4) void gemm_partial(const float* __restrict__ adj,
                                                       const __bf16* __restrict__ Bhi,
                                                       const __bf16* __restrict__ Blo,
                                                       float* __restrict__ partial) {
    const int lane = threadIdx.x & 63;
    const int wv = threadIdx.x >> 6;   // wave -> 16-row group
    const int rt = blockIdx.x & 255;   // row-tile 0..255
    const int ks = blockIdx.x >> 8;    // k-split 0..7
    const int rbase = rt * 64 + wv * 16;
    const int rq = lane & 15;          // A row within group
    const int kq = lane >> 4;          // k-quarter 0..3

    f32x4 acc[4];
#pragma unroll
    for (int t = 0; t < 4; ++t) acc[t] = f32x4{0.f, 0.f, 0.f, 0.f};

    const float* ap = adj + (size_t)(rbase + rq) * NROWS + ks * KCH + kq * 8;
    const int kk0 = ks * KCH;

    for (int kk = 0; kk < KCH; kk += 32) {
        // B fragments (L2-resident packed bf16), 8 x 16B coalesced loads
        const size_t bb = ((size_t)((kk0 + kk) >> 5) * 4) * 512 + (size_t)lane * 8;
        bf16x8 bh[4], bl[4];
#pragma unroll
        for (int t = 0; t < 4; ++t) {
            bh[t] = *(const bf16x8*)(Bhi + bb + (size_t)t * 512);
            bl[t] = *(const bf16x8*)(Blo + bb + (size_t)t * 512);
        }
        // A: 8 fp32 per lane, contiguous 32B, plain loads (L1 merges v0/v1)
        const f32x4* app = (const f32x4*)(ap + kk);
        f32x4 v0 = app[0];
        f32x4 v1 = app[1];
        bf16x8 ah, al;
        split8v(v0, v1, ah, al);

#pragma unroll
        for (int t = 0; t < 4; ++t) {
            acc[t] = mfma16(ah, bh[t], acc[t]);
            acc[t] = mfma16(ah, bl[t], acc[t]);
            acc[t] = mfma16(al, bh[t], acc[t]);
        }
    }

    // C/D layout: col = lane&15, row = (lane>>4)*4 + reg   [m89-verified]
    float* pp = partial + (size_t)ks * (NROWS * HID) + (size_t)rbase * HID;
#pragma unroll
    for (int t = 0; t < 4; ++t)
#pragma unroll
        for (int r = 0; r < 4; ++r)
            __builtin_nontemporal_store(acc[t][r],
                pp + (kq * 4 + r) * HID + t * 16 + (lane & 15));
}

// ---------------------------------------------------------------------------
// reduce_dense: agg_r = sum_ks partial[ks][r]; x_out[r] = tanh([agg_r|x_r] @ W)
// W [128,64] staged in LDS; lane = output column; row values via __shfl.
// ---------------------------------------------------------------------------
__global__ __launch_bounds__(256) void reduce_dense(const float* __restrict__ partial,
                                                    const float* __restrict__ xin,
                                                    const float* __restrict__ W,
                                                    float* __restrict__ xout) {
    __shared__ float wsm[128 * 64];  // 32 KB
    const f32x4* wsrc = (const f32x4*)W;
    f32x4* wdst = (f32x4*)wsm;
#pragma unroll
    for (int i = 0; i < 8; ++i) wdst[threadIdx.x + 256 * i] = wsrc[threadIdx.x + 256 * i];
    __syncthreads();

    const int lane = threadIdx.x & 63;
    const int wv = threadIdx.x >> 6;
    const int r0 = blockIdx.x * 32 + wv * 8;
#pragma unroll 2
    for (int i = 0; i < 8; ++i) {
        const int r = r0 + i;
        float av = 0.f;
#pragma unroll
        for (int ks = 0; ks < KSPLIT; ++ks)
            av += partial[(size_t)ks * (NROWS * HID) + (size_t)r * HID + lane];
        const float xv = xin[(size_t)r * HID + lane];
        float z = 0.f;
#pragma unroll
        for (int j = 0; j < 64; ++j) z += __shfl(av, j) * wsm[j * 64 + lane];
#pragma unroll
        for (int j = 0; j < 64; ++j) z += __shfl(xv, j) * wsm[(64 + j) * 64 + lane];
        xout[(size_t)r * HID + lane] = tanhf(z);
    }
}

extern "C" void kernel_launch(void* const* d_in, const int* in_sizes, int n_in,
                              void* d_out, int out_size, void* d_ws, size_t ws_size,
                              hipStream_t stream) {
    const float* x0 = (const float*)d_in[0];   // user_embs [16384,64]
    const float* adj = (const float*)d_in[1];  // adj [16384,16384]
    const float* W = (const float*)d_in[2];    // W [2,128,64]
    float* out = (float*)d_out;

    char* ws = (char*)d_ws;
    __bf16* Bhi = (__bf16*)(ws);                       // 2 MB
    __bf16* Blo = (__bf16*)(ws + (2u << 20));          // 2 MB
    float* partial = (float*)(ws + (4u << 20));        // 32 MB (8 x 4 MB)
    float* x1 = (float*)(ws + (36u << 20));            // 4 MB

    // hop 0
    pack_b<<<512, 256, 0, stream>>>(x0, Bhi, Blo);
    gemm_partial<<<KSPLIT * 256, 256, 0, stream>>>(adj, Bhi, Blo, partial);
    reduce_dense<<<512, 256, 0, stream>>>(partial, x0, W, x1);
    // hop 1
    pack_b<<<512, 256, 0, stream>>>(x1, Bhi, Blo);
    gemm_partial<<<KSPLIT * 256, 256, 0, stream>>>(adj, Bhi, Blo, partial);
    reduce_dense<<<512, 256, 0, stream>>>(partial, x1, W + 128 * 64, out);
}

// Round 6
// 591.125 us; speedup vs baseline: 1.5454x; 1.3659x over previous
//
#include <hip/hip_runtime.h>
#include <hip/hip_bf16.h>
#include <math.h>

#define NROWS 16384
#define HID 64
#define KSPLIT 8
#define KCH (NROWS / KSPLIT)  // 2048

typedef __attribute__((ext_vector_type(8))) __bf16 bf16x8;
typedef __attribute__((ext_vector_type(4))) float f32x4;

__device__ inline f32x4 mfma16(bf16x8 a, bf16x8 b, f32x4 c) {
    return __builtin_amdgcn_mfma_f32_16x16x32_bf16(a, b, c, 0, 0, 0);
}

__device__ inline void split8v(const f32x4 v0, const f32x4 v1, bf16x8& h, bf16x8& l) {
    float f[8] = {v0[0], v0[1], v0[2], v0[3], v1[0], v1[1], v1[2], v1[3]};
#pragma unroll
    for (int j = 0; j < 8; ++j) {
        __bf16 hh = (__bf16)f[j];
        h[j] = hh;
        l[j] = (__bf16)(f[j] - (float)hh);
    }
}

// ---------------------------------------------------------------------------
// pack_b: x [16384,64] fp32 row-major  ->  MFMA B-fragment-ordered bf16 hi/lo.
// Packed index: (((kb*4 + t)*64 + lane)*8 + j)
//   holds x[kb*32 + (lane>>4)*8 + j][t*16 + (lane&15)]
// ---------------------------------------------------------------------------
__global__ __launch_bounds__(256) void pack_b(const float* __restrict__ x,
                                              __bf16* __restrict__ hi,
                                              __bf16* __restrict__ lo) {
    __shared__ float tile[32 * 64];
    const int kb = blockIdx.x;  // 0..511, 32 k-rows each
    const f32x4* src = (const f32x4*)(x + (size_t)kb * 32 * 64);
    f32x4* dst = (f32x4*)tile;
    dst[threadIdx.x] = src[threadIdx.x];
    dst[threadIdx.x + 256] = src[threadIdx.x + 256];
    __syncthreads();
    const int t = threadIdx.x >> 6;    // n-tile 0..3
    const int l = threadIdx.x & 63;    // consumer lane
    const int col = (t << 4) + (l & 15);
    const int krow = (l >> 4) * 8;
    bf16x8 h8, l8;
#pragma unroll
    for (int j = 0; j < 8; ++j) {
        float v = tile[(krow + j) * 64 + col];
        __bf16 hh = (__bf16)v;
        h8[j] = hh;
        l8[j] = (__bf16)(v - (float)hh);
    }
    const size_t base = (((size_t)kb * 4 + t) * 64 + l) * 8;
    *(bf16x8*)(hi + base) = h8;
    *(bf16x8*)(lo + base) = l8;
}

// ---------------------------------------------------------------------------
// gemm_partial: partial[ks] = adj[:, ks-chunk] @ x[ks-chunk, :]
// blockIdx = ks*128 + rt. Block = 128 rows x 2048 k; 4 waves x 32 rows
// (2 row-groups of 16), ALL waves share the same k-range so the 8 B-fragment
// loads per k-step are L1-shared across waves. Per k-step per wave:
// 24 MFMA / 12 global loads (r1's proven density) vs r5's 12/10.
// adj loads plain (L1 merges the v0/v1 half-line pair; nt double-fetched).
// Partial stores nt (no reuse, keep L2 for B).
// ---------------------------------------------------------------------------
__global__ __launch_bounds__(256, 4) void gemm_partial(const float* __restrict__ adj,
                                                       const __bf16* __restrict__ Bhi,
                                                       const __bf16* __restrict__ Blo,
                                                       float* __restrict__ partial) {
    const int lane = threadIdx.x & 63;
    const int wv = threadIdx.x >> 6;   // wave -> 32-row group
    const int rt = blockIdx.x & 127;   // row-tile 0..127
    const int ks = blockIdx.x >> 7;    // k-split 0..7
    const int rbase = rt * 128 + wv * 32;
    const int rq = lane & 15;          // A row within 16-row group
    const int kq = lane >> 4;          // k-quarter 0..3

    f32x4 acc[2][4];
#pragma unroll
    for (int g = 0; g < 2; ++g)
#pragma unroll
        for (int t = 0; t < 4; ++t) acc[g][t] = f32x4{0.f, 0.f, 0.f, 0.f};

    const float* a0p = adj + (size_t)(rbase + rq) * NROWS + ks * KCH + kq * 8;
    const float* a1p = a0p + (size_t)16 * NROWS;
    const int kk0 = ks * KCH;

    for (int kk = 0; kk < KCH; kk += 32) {
        // B fragments (L2-resident packed bf16), 8 x 16B loads, wave-shared
        const size_t bb = ((size_t)((kk0 + kk) >> 5) * 4) * 512 + (size_t)lane * 8;
        bf16x8 bh[4], bl[4];
#pragma unroll
        for (int t = 0; t < 4; ++t) {
            bh[t] = *(const bf16x8*)(Bhi + bb + (size_t)t * 512);
            bl[t] = *(const bf16x8*)(Blo + bb + (size_t)t * 512);
        }
        // A: two 16-row groups, 8 fp32 per lane each, contiguous 32B
        const f32x4* a0 = (const f32x4*)(a0p + kk);
        const f32x4* a1 = (const f32x4*)(a1p + kk);
        f32x4 v0 = a0[0], v1 = a0[1];
        f32x4 w0 = a1[0], w1 = a1[1];
        bf16x8 ah0, al0, ah1, al1;
        split8v(v0, v1, ah0, al0);
        split8v(w0, w1, ah1, al1);

#pragma unroll
        for (int t = 0; t < 4; ++t) {
            acc[0][t] = mfma16(ah0, bh[t], acc[0][t]);
            acc[0][t] = mfma16(ah0, bl[t], acc[0][t]);
            acc[0][t] = mfma16(al0, bh[t], acc[0][t]);
            acc[1][t] = mfma16(ah1, bh[t], acc[1][t]);
            acc[1][t] = mfma16(ah1, bl[t], acc[1][t]);
            acc[1][t] = mfma16(al1, bh[t], acc[1][t]);
        }
    }

    // C/D layout: col = lane&15, row = (lane>>4)*4 + reg   [m89-verified]
    float* pp = partial + (size_t)ks * (NROWS * HID) + (size_t)rbase * HID;
#pragma unroll
    for (int g = 0; g < 2; ++g)
#pragma unroll
        for (int t = 0; t < 4; ++t)
#pragma unroll
            for (int r = 0; r < 4; ++r)
                __builtin_nontemporal_store(acc[g][t][r],
                    pp + (g * 16 + kq * 4 + r) * HID + t * 16 + (lane & 15));
}

// ---------------------------------------------------------------------------
// reduce_dense: agg_r = sum_ks partial[ks][r]; x_out[r] = tanh([agg_r|x_r] @ W)
// W [128,64] staged in LDS; lane = output column; row values via __shfl.
// ---------------------------------------------------------------------------
__global__ __launch_bounds__(256) void reduce_dense(const float* __restrict__ partial,
                                                    const float* __restrict__ xin,
                                                    const float* __restrict__ W,
                                                    float* __restrict__ xout) {
    __shared__ float wsm[128 * 64];  // 32 KB
    const f32x4* wsrc = (const f32x4*)W;
    f32x4* wdst = (f32x4*)wsm;
#pragma unroll
    for (int i = 0; i < 8; ++i) wdst[threadIdx.x + 256 * i] = wsrc[threadIdx.x + 256 * i];
    __syncthreads();

    const int lane = threadIdx.x & 63;
    const int wv = threadIdx.x >> 6;
    const int r0 = blockIdx.x * 32 + wv * 8;
#pragma unroll 2
    for (int i = 0; i < 8; ++i) {
        const int r = r0 + i;
        float av = 0.f;
#pragma unroll
        for (int ks = 0; ks < KSPLIT; ++ks)
            av += partial[(size_t)ks * (NROWS * HID) + (size_t)r * HID + lane];
        const float xv = xin[(size_t)r * HID + lane];
        float z = 0.f;
#pragma unroll
        for (int j = 0; j < 64; ++j) z += __shfl(av, j) * wsm[j * 64 + lane];
#pragma unroll
        for (int j = 0; j < 64; ++j) z += __shfl(xv, j) * wsm[(64 + j) * 64 + lane];
        xout[(size_t)r * HID + lane] = tanhf(z);
    }
}

extern "C" void kernel_launch(void* const* d_in, const int* in_sizes, int n_in,
                              void* d_out, int out_size, void* d_ws, size_t ws_size,
                              hipStream_t stream) {
    const float* x0 = (const float*)d_in[0];   // user_embs [16384,64]
    const float* adj = (const float*)d_in[1];  // adj [16384,16384]
    const float* W = (const float*)d_in[2];    // W [2,128,64]
    float* out = (float*)d_out;

    char* ws = (char*)d_ws;
    __bf16* Bhi = (__bf16*)(ws);                       // 2 MB
    __bf16* Blo = (__bf16*)(ws + (2u << 20));          // 2 MB
    float* partial = (float*)(ws + (4u << 20));        // 32 MB (8 x 4 MB)
    float* x1 = (float*)(ws + (36u << 20));            // 4 MB

    // hop 0
    pack_b<<<512, 256, 0, stream>>>(x0, Bhi, Blo);
    gemm_partial<<<KSPLIT * 128, 256, 0, stream>>>(adj, Bhi, Blo, partial);
    reduce_dense<<<512, 256, 0, stream>>>(partial, x0, W, x1);
    // hop 1
    pack_b<<<512, 256, 0, stream>>>(x1, Bhi, Blo);
    gemm_partial<<<KSPLIT * 128, 256, 0, stream>>>(adj, Bhi, Blo, partial);
    reduce_dense<<<512, 256, 0, stream>>>(partial, x1, W + 128 * 64, out);
}